// Round 5
// baseline (283.433 us; speedup 1.0000x reference)
//
#include <hip/hip_runtime.h>
#include <hip/hip_bf16.h>

// GCN 2-layer forward — global-atomic counting-sort CSR build + bf16
// intermediates.
// R14: (1) layer12/gather2 reverted to R11 exact structure (43us, occ 53%,
// VGPR 36) — R13 wave-window preload cost VGPR 36->48, occ 53->40%, 43->47us.
// Law confirmed 3x: TLP beats per-wave pipelining here. (2) CSR build
// rewritten: bucketed LDS sort (bfill+bfine, 196-block serial atomic passes)
// -> flat counting sort: k_hist (1M global atomics on 100K counters),
// k_bsum+k_bscan (bucket bases), k_rowptr (per-bucket scan), k_scatter
// (atomicAdd cursor + scattered store). All phases BW-trivial (4-8 MB).
// Scatter order irrelevant: gather sums all neighbors.

constexpr int N = 100000;
constexpr int E = 1000000;
constexpr int NB = (N + 511) / 512;   // 196 buckets of 512 nodes
constexpr int NPW = 6;                // nodes per wave (layer12/gather2)
constexpr int NW = (N + NPW - 1) / NPW;        // 16667 waves
constexpr int NWBLK = (NW + 3) / 4;            // 4167 blocks

__device__ __forceinline__ float bflo(unsigned u) { return __uint_as_float(u << 16); }
__device__ __forceinline__ float bfhi(unsigned u) { return __uint_as_float(u & 0xffff0000u); }

// lgkmcnt(0) only: vmcnt=63, expcnt=7, lgkmcnt=0  ->  0xc07f.
// sched_barrier keeps the compiler from floating LDS reads above it.
__device__ __forceinline__ void wait_lgkm0() {
    __builtin_amdgcn_s_waitcnt(0xc07f);
    __builtin_amdgcn_sched_barrier(0);
}

// Per-node degree histogram. 1M atomics over 100K counters (~10/addr).
__global__ void k_hist(const int* __restrict__ dst, int* __restrict__ cnt) {
    int i = blockIdx.x * blockDim.x + threadIdx.x;
    int stride = gridDim.x * blockDim.x;
    for (; i < E; i += stride) atomicAdd(&cnt[dst[i]], 1);
}

// Per-bucket sums (196 blocks x 512): block-reduce of 512 counts.
__global__ void k_bsum(const int* __restrict__ cnt, int* __restrict__ bsum) {
    __shared__ int ws[8];
    int b = blockIdx.x, t = threadIdx.x, lane = t & 63;
    int node = b * 512 + t;
    int v = (node < N) ? cnt[node] : 0;
#pragma unroll
    for (int off = 1; off < 64; off <<= 1) v += __shfl_xor(v, off);
    if (lane == 0) ws[t >> 6] = v;
    __syncthreads();
    if (t == 0) {
        int s = 0;
#pragma unroll
        for (int i = 0; i < 8; ++i) s += ws[i];
        bsum[b] = s;
    }
}

// Exclusive scan of 196 bucket sums (1 block x 256).
__global__ void k_bscan(const int* __restrict__ bsum, int* __restrict__ bbase) {
    __shared__ int ws[4];
    int t = threadIdx.x, lane = t & 63;
    int h = (t < NB) ? bsum[t] : 0;
    int v = h;
#pragma unroll
    for (int off = 1; off < 64; off <<= 1) {
        int u = __shfl_up(v, off);
        if (lane >= off) v += u;
    }
    if (lane == 63) ws[t >> 6] = v;
    __syncthreads();
    int add = 0;
    for (int i = 0; i < (t >> 6); ++i) add += ws[i];
    if (t < NB) bbase[t] = v + add - h;          // exclusive
}

// Per-bucket scan -> row_ptr, cursor (scatter cursors), dinv.
__global__ void k_rowptr(const int* __restrict__ cnt, const int* __restrict__ bbase,
                         int* __restrict__ row_ptr, int* __restrict__ cursor,
                         float* __restrict__ dinv) {
    __shared__ int ws[8];
    int b = blockIdx.x, t = threadIdx.x, lane = t & 63;
    int node = b * 512 + t;
    int h = (node < N) ? cnt[node] : 0;
    int v = h;
#pragma unroll
    for (int off = 1; off < 64; off <<= 1) {
        int u = __shfl_up(v, off);
        if (lane >= off) v += u;
    }
    if (lane == 63) ws[t >> 6] = v;
    __syncthreads();
    int add = 0;
    for (int i = 0; i < (t >> 6); ++i) add += ws[i];
    int ex = v + add - h;                        // exclusive within bucket
    if (node < N) {
        int rp = bbase[b] + ex;
        row_ptr[node] = rp;
        cursor[node] = rp;
        dinv[node] = rsqrtf((float)(h + 1));
    }
    if (b == 0 && t == 0) row_ptr[N] = E;
}

// Edge scatter: pos = cursor[dst]++, csr_src[pos] = src.
__global__ void k_scatter(const int* __restrict__ src, const int* __restrict__ dst,
                          int* __restrict__ cursor, int* __restrict__ csr_src) {
    int i = blockIdx.x * blockDim.x + threadIdx.x;
    int stride = gridDim.x * blockDim.x;
    for (; i < E; i += stride) {
        int d = dst[i];
        int s = src[i];
        int pos = atomicAdd(&cursor[d], 1);
        csr_src[pos] = s;
    }
}

// h1s[row][c] = (X[row] . W1[:,c]) * dinv[row], stored bf16 (packed stores).
// Register double-buffer: next sweep's 4 X rows issued before the current
// tile's FMAs; lgkm-only wait keeps them in flight over compute.
__global__ void k_gemm1(const float* __restrict__ X, const float* __restrict__ W1,
                        const float* __restrict__ dinv, __hip_bfloat16* __restrict__ h1s,
                        __hip_bfloat16* __restrict__ h2s) {
    __shared__ float sX[4][4][64];              // [wave][row][feat]
    int t = threadIdx.x;
    int lane = t & 63;
    int w = t >> 6;
    int wid = (blockIdx.x * 256 + t) >> 6;      // 4096 waves
    if (blockIdx.x == 0) {
        if (t < 64) h1s[(size_t)N * 64 + t] = __float2bfloat16(0.f);
        if (t < 16) h2s[(size_t)N * 16 + t] = __float2bfloat16(0.f);
    }
    float w1[64];
#pragma unroll
    for (int k = 0; k < 64; ++k) w1[k] = W1[k * 64 + lane];
    constexpr int STRIDE = 4096 * 4;
    int r4 = wid * 4;
    float x0 = X[(size_t)r4 * 64 + lane];
    float x1 = X[(size_t)(r4 + 1) * 64 + lane];
    float x2 = X[(size_t)(r4 + 2) * 64 + lane];
    float x3 = X[(size_t)(r4 + 3) * 64 + lane];
    for (; r4 < N; r4 += STRIDE) {
        int rn = r4 + STRIDE;
        float y0 = 0.f, y1 = 0.f, y2 = 0.f, y3 = 0.f;
        if (rn < N) {                           // prefetch next sweep
            y0 = X[(size_t)rn * 64 + lane];
            y1 = X[(size_t)(rn + 1) * 64 + lane];
            y2 = X[(size_t)(rn + 2) * 64 + lane];
            y3 = X[(size_t)(rn + 3) * 64 + lane];
        }
        float dv0 = dinv[r4], dv1 = dinv[r4 + 1], dv2 = dinv[r4 + 2], dv3 = dinv[r4 + 3];
        sX[w][0][lane] = x0; sX[w][1][lane] = x1;
        sX[w][2][lane] = x2; sX[w][3][lane] = x3;
        wait_lgkm0();                           // y*/dv* stay in flight
        float acc0 = 0.f, acc1 = 0.f, acc2 = 0.f, acc3 = 0.f;
#pragma unroll
        for (int k = 0; k < 64; ++k) {          // 4 independent FMA chains
            float wk = w1[k];
            acc0 = fmaf(sX[w][0][k], wk, acc0);
            acc1 = fmaf(sX[w][1][k], wk, acc1);
            acc2 = fmaf(sX[w][2][k], wk, acc2);
            acc3 = fmaf(sX[w][3][k], wk, acc3);
        }
        acc0 *= dv0; acc1 *= dv1; acc2 *= dv2; acc3 *= dv3;
        float up0 = __shfl_xor(acc0, 1);
        float up1 = __shfl_xor(acc1, 1);
        float up2 = __shfl_xor(acc2, 1);
        float up3 = __shfl_xor(acc3, 1);
        if (!(lane & 1)) {
            __hip_bfloat162 p;
            p.x = __float2bfloat16(acc0); p.y = __float2bfloat16(up0);
            *(__hip_bfloat162*)(h1s + (size_t)r4 * 64 + lane) = p;
            p.x = __float2bfloat16(acc1); p.y = __float2bfloat16(up1);
            *(__hip_bfloat162*)(h1s + (size_t)(r4 + 1) * 64 + lane) = p;
            p.x = __float2bfloat16(acc2); p.y = __float2bfloat16(up2);
            *(__hip_bfloat162*)(h1s + (size_t)(r4 + 2) * 64 + lane) = p;
            p.x = __float2bfloat16(acc3); p.y = __float2bfloat16(up3);
            *(__hip_bfloat162*)(h1s + (size_t)(r4 + 3) * 64 + lane) = p;
        }
        x0 = y0; x1 = y1; x2 = y2; x3 = y3;
    }
}

// Fused: gather layer-1 (CSR), +b1, relu, y1@W2, scale -> h2s (bf16).
// Wave handles NPW contiguous nodes. 8 edges per uint4 load, 2-deep unroll;
// dummy zero row N pads — no predication, no divergence. (R11 structure.)
__global__ void k_layer12(const int* __restrict__ row_ptr, const int* __restrict__ csr_src,
                          const float* __restrict__ dinv, const __hip_bfloat16* __restrict__ h1s,
                          const float* __restrict__ b1, const float* __restrict__ W2,
                          __hip_bfloat16* __restrict__ h2s) {
    __shared__ float sy[4][8][72];
    int t = threadIdx.x;
    int lane = t & 63;
    int w = t >> 6;
    int g8 = lane >> 3;                         // edge sub-slot
    int qo = (lane & 7) << 4;                   // byte offset of 16B feat slice
    int g16 = lane >> 4, c16 = lane & 15;       // W2-stage layout
    int wid = blockIdx.x * 4 + w;
    int d0 = wid * NPW;
    if (d0 >= N) return;
    int dend = min(d0 + NPW, N);
    float w2[16];
#pragma unroll
    for (int j = 0; j < 16; ++j) w2[j] = W2[(g16 * 16 + j) * 16 + c16];
    float b1v = b1[lane];
    const char* Hb = (const char*)h1s;

    int rp0 = row_ptr[d0];
    for (int d = d0; d < dend; ++d) {
        int rp1 = row_ptr[d + 1];
        float dv = dinv[d];
        float a[8] = {0, 0, 0, 0, 0, 0, 0, 0};
        if (g8 == 0) {                          // self term (one 8-lane load)
            uint4 u = *(const uint4*)(Hb + (((unsigned)d << 7) | qo));
            a[0] = bflo(u.x); a[1] = bfhi(u.x); a[2] = bflo(u.y); a[3] = bfhi(u.y);
            a[4] = bflo(u.z); a[5] = bfhi(u.z); a[6] = bflo(u.w); a[7] = bfhi(u.w);
        }
        for (int base = rp0; base < rp1; base += 64) {   // wave-uniform bounds
            int nloc = min(64, rp1 - base);
            int sidx = (lane < nloc) ? csr_src[base + lane] : N;   // pad -> zero row
            int steps = (nloc + 15) >> 4;       // 16 edges / iter, 2 loads in flight
            for (int j = 0; j < steps; ++j) {
                int b0 = (j << 4) | g8;
                int s0 = __shfl(sidx, b0);
                int s1 = __shfl(sidx, b0 | 8);
                uint4 u0 = *(const uint4*)(Hb + (((unsigned)s0 << 7) | qo));
                uint4 u1 = *(const uint4*)(Hb + (((unsigned)s1 << 7) | qo));
                a[0] += bflo(u0.x); a[1] += bfhi(u0.x); a[2] += bflo(u0.y); a[3] += bfhi(u0.y);
                a[4] += bflo(u0.z); a[5] += bfhi(u0.z); a[6] += bflo(u0.w); a[7] += bfhi(u0.w);
                a[0] += bflo(u1.x); a[1] += bfhi(u1.x); a[2] += bflo(u1.y); a[3] += bfhi(u1.y);
                a[4] += bflo(u1.z); a[5] += bfhi(u1.z); a[6] += bflo(u1.w); a[7] += bfhi(u1.w);
            }
        }
        rp0 = rp1;
        // LDS transpose: partials (8 groups x 64 feats) -> y[feat=lane]
        float* row = &sy[w][g8][(lane & 7) << 3];
        *(float4*)row = make_float4(a[0], a[1], a[2], a[3]);
        *(float4*)(row + 4) = make_float4(a[4], a[5], a[6], a[7]);
        wait_lgkm0();                           // within-wave LDS order only
        float ysum = sy[w][0][lane] + sy[w][1][lane] + sy[w][2][lane] + sy[w][3][lane]
                   + sy[w][4][lane] + sy[w][5][lane] + sy[w][6][lane] + sy[w][7][lane];
        float y = fmaxf(fmaf(dv, ysum, b1v), 0.f);
        // h2[c] = sum_k y[k]*W2[k][c]; group g16 covers k = g16*16..+15
        float o = 0.f;
#pragma unroll
        for (int j = 0; j < 16; ++j) o = fmaf(__shfl(y, (lane & 48) | j), w2[j], o);
        o += __shfl_xor(o, 16);
        o += __shfl_xor(o, 32);
        o *= dv;
        float oup = __shfl_xor(o, 1);
        if (lane < 16 && !(lane & 1)) {
            __hip_bfloat162 p;
            p.x = __float2bfloat16(o);
            p.y = __float2bfloat16(oup);
            *(__hip_bfloat162*)(h2s + (size_t)d * 16 + lane) = p;
        }
    }
}

// out[d] = dinv[d]*(h2s[d] + sum_in h2s[s]) + b2.  16 edges per step (uint2,
// 4 lanes/edge), dummy-row padding, float4 stores. (R11 structure.)
__global__ void k_gather2(const int* __restrict__ row_ptr, const int* __restrict__ csr_src,
                          const float* __restrict__ dinv, const __hip_bfloat16* __restrict__ h2s,
                          const float* __restrict__ b2, float* __restrict__ out) {
    int t = threadIdx.x;
    int lane = t & 63;
    int g4 = lane >> 2;                         // edge slot within step
    int q2 = lane & 3;                          // 8B feat slice
    int qo = q2 << 3;
    int wid = blockIdx.x * 4 + (t >> 6);
    int d0 = wid * NPW;
    if (d0 >= N) return;
    int dend = min(d0 + NPW, N);
    float b2v[4];
#pragma unroll
    for (int k = 0; k < 4; ++k) b2v[k] = b2[q2 * 4 + k];
    const char* Hb = (const char*)h2s;

    int rp0 = row_ptr[d0];
    for (int d = d0; d < dend; ++d) {
        int rp1 = row_ptr[d + 1];
        float dv = dinv[d];
        float a[4] = {0, 0, 0, 0};
        if (g4 == 0) {                          // self term
            uint2 u = *(const uint2*)(Hb + (((unsigned)d << 5) | qo));
            a[0] = bflo(u.x); a[1] = bfhi(u.x); a[2] = bflo(u.y); a[3] = bfhi(u.y);
        }
        for (int base = rp0; base < rp1; base += 64) {
            int nloc = min(64, rp1 - base);
            int sidx = (lane < nloc) ? csr_src[base + lane] : N;
            int steps = (nloc + 15) >> 4;
            for (int j = 0; j < steps; ++j) {
                int s = __shfl(sidx, (j << 4) | g4);
                uint2 u = *(const uint2*)(Hb + (((unsigned)s << 5) | qo));
                a[0] += bflo(u.x); a[1] += bfhi(u.x);
                a[2] += bflo(u.y); a[3] += bfhi(u.y);
            }
        }
        rp0 = rp1;
#pragma unroll
        for (int k = 0; k < 4; ++k) {
            a[k] += __shfl_xor(a[k], 4);
            a[k] += __shfl_xor(a[k], 8);
            a[k] += __shfl_xor(a[k], 16);
            a[k] += __shfl_xor(a[k], 32);
        }
        if (lane < 4) {
            float4 r;
            r.x = fmaf(dv, a[0], b2v[0]);
            r.y = fmaf(dv, a[1], b2v[1]);
            r.z = fmaf(dv, a[2], b2v[2]);
            r.w = fmaf(dv, a[3], b2v[3]);
            *(float4*)(out + (size_t)d * 16 + q2 * 4) = r;
        }
    }
}

extern "C" void kernel_launch(void* const* d_in, const int* in_sizes, int n_in,
                              void* d_out, int out_size, void* d_ws, size_t ws_size,
                              hipStream_t stream) {
    const float* X  = (const float*)d_in[0];
    const int*   ei = (const int*)d_in[1];  // [2, E] int32: src then dst
    const float* W1 = (const float*)d_in[2];
    const float* b1 = (const float*)d_in[3];
    const float* W2 = (const float*)d_in[4];
    const float* b2 = (const float*)d_in[5];
    float* out = (float*)d_out;

    int* cnt     = (int*)d_ws;                     // N   (memset 0)
    int* bsum    = cnt + N;                        // 256 (memset 0, same region)
    int* bbase   = bsum + 256;                     // 256
    int* row_ptr = bbase + 256;                    // N+4
    int* cursor  = row_ptr + N + 4;                // N
    int* csr_src = cursor + N;                     // E
    float* dinv  = (float*)(csr_src + E);          // N
    __hip_bfloat16* h1s = (__hip_bfloat16*)(dinv + N);  // (N+1)*64, 16B-aligned
    __hip_bfloat16* h2s = h1s + (size_t)(N + 1) * 64;   // (N+1)*16, 16B-aligned

    const int* src = ei;
    const int* dst = ei + E;

    hipMemsetAsync(cnt, 0, (N + 256) * sizeof(int), stream);
    k_hist<<<1024, 512, 0, stream>>>(dst, cnt);
    k_bsum<<<NB, 512, 0, stream>>>(cnt, bsum);
    k_bscan<<<1, 256, 0, stream>>>(bsum, bbase);
    k_rowptr<<<NB, 512, 0, stream>>>(cnt, bbase, row_ptr, cursor, dinv);
    k_scatter<<<1024, 512, 0, stream>>>(src, dst, cursor, csr_src);
    k_gemm1<<<1024, 256, 0, stream>>>(X, W1, dinv, h1s, h2s);
    k_layer12<<<NWBLK, 256, 0, stream>>>(row_ptr, csr_src, dinv, h1s, b1, W2, h2s);
    k_gather2<<<NWBLK, 256, 0, stream>>>(row_ptr, csr_src, dinv, h2s, b2, out);
}

// Round 6
// 180.799 us; speedup vs baseline: 1.5677x; 1.5677x over previous
//
#include <hip/hip_runtime.h>
#include <hip/hip_bf16.h>

// GCN 2-layer forward — bucketed CSR build + bf16 intermediates.
// R15: revert R14's flat counting sort (k_scatter: 1M scattered 4B stores ->
// 70MB of partial-line HBM writebacks @1TB/s = 74us; bucketed LDS staging is
// load-bearing). Back to R11 build (bfill/bfine, 512thr, CHUNK 2048).
// One isolated change vs R11: NPW 6->4 in layer12/gather2 (+50% waves).
// layer12 is latency-bound (VALUBusy 44%, occ 53%); TLP is the only lever
// that has moved it (R10/R13 per-wave pipelining both regressed).

constexpr int N = 100000;
constexpr int E = 1000000;
constexpr int NB = (N + 511) / 512;   // 196 buckets of 512 dst nodes
constexpr int CAP = 6144;             // mean fill 5102, sd ~71 -> 14 sigma
constexpr int CSTRIDE = 32;           // cursor padding: 1 per 128B line
constexpr int CHUNK = 2048;           // edges per k_bfill block
constexpr int NBLK = (E + CHUNK - 1) / CHUNK;  // 489
constexpr int BT = 512;               // build-kernel threads
constexpr int NPW = 4;                // nodes per wave (layer12/gather2)
constexpr int NW = (N + NPW - 1) / NPW;        // 25000 waves
constexpr int NWBLK = (NW + 3) / 4;            // 6250 blocks

__device__ __forceinline__ float bflo(unsigned u) { return __uint_as_float(u << 16); }
__device__ __forceinline__ float bfhi(unsigned u) { return __uint_as_float(u & 0xffff0000u); }

// lgkmcnt(0) only: vmcnt=63, expcnt=7, lgkmcnt=0  ->  0xc07f.
// sched_barrier keeps the compiler from floating LDS reads above it.
__device__ __forceinline__ void wait_lgkm0() {
    __builtin_amdgcn_s_waitcnt(0xc07f);
    __builtin_amdgcn_sched_barrier(0);
}

// Two-pass LDS-binned scatter into coarse buckets.
// pack = (dst&511)<<17 | src  (src < 2^17).
__global__ void k_bfill(const int* __restrict__ src, const int* __restrict__ dst,
                        int* __restrict__ cursor, int* __restrict__ bkt) {
    __shared__ int hist[256];
    __shared__ int lbase[256];
    __shared__ int gbase[256];
    __shared__ int lcur[256];
    __shared__ int ws[8];
    __shared__ int stage[CHUNK];
    __shared__ unsigned char sbkt[CHUNK];
    int t = threadIdx.x;
    int lane = t & 63;
    int e0 = blockIdx.x * CHUNK;
    int cnt = min(CHUNK, E - e0);

    if (t < 256) hist[t] = 0;
    __syncthreads();
    for (int j = t; j < cnt; j += BT)
        atomicAdd(&hist[dst[e0 + j] >> 9], 1);
    __syncthreads();
    int h = (t < 256) ? hist[t] : 0;
    int v = h;                                  // wave-scan (waves 4-7 scan 0s)
#pragma unroll
    for (int off = 1; off < 64; off <<= 1) {
        int u = __shfl_up(v, off);
        if (lane >= off) v += u;
    }
    if (lane == 63) ws[t >> 6] = v;
    __syncthreads();
    int add = 0;
    for (int i = 0; i < (t >> 6); ++i) add += ws[i];
    int inc = v + add;
    if (t < 256) { lbase[t] = inc - h; lcur[t] = 0; }
    if (t < NB) gbase[t] = h ? atomicAdd(&cursor[t * CSTRIDE], h) : 0;
    __syncthreads();
    for (int j = t; j < cnt; j += BT) {         // stage bucket-sorted
        int d = dst[e0 + j];
        int b = d >> 9;
        int pos = lbase[b] + atomicAdd(&lcur[b], 1);
        stage[pos] = ((d & 511) << 17) | src[e0 + j];
        sbkt[pos] = (unsigned char)b;
    }
    __syncthreads();
    for (int j = t; j < cnt; j += BT) {         // contiguous-run copy out
        int b = sbkt[j];
        int gpos = gbase[b] + (j - lbase[b]);
        if (gpos < CAP) bkt[b * CAP + gpos] = stage[j];
    }
}

// One workgroup (512 thr) per bucket: masked reduce for global base, LDS
// histogram (1 thread = 1 bin), wave+ws scan, write row_ptr/dinv, place csr.
__global__ void k_bfine(const int* __restrict__ cursor, const int* __restrict__ bkt,
                        int* __restrict__ row_ptr, float* __restrict__ dinv,
                        int* __restrict__ csr_src) {
    __shared__ int cnt[512];
    __shared__ int excl[512];
    __shared__ int ws[8];
    int b = blockIdx.x;
    int t = threadIdx.x;
    int lane = t & 63;
    int c = (t < NB) ? cursor[t * CSTRIDE] : 0;
    int mv = (t < b) ? c : 0;                   // base = sum of buckets < b
#pragma unroll
    for (int off = 1; off < 64; off <<= 1) mv += __shfl_xor(mv, off);
    if (lane == 0) ws[t >> 6] = mv;
    cnt[t] = 0;
    __syncthreads();
    int base = ws[0] + ws[1] + ws[2] + ws[3] + ws[4] + ws[5] + ws[6] + ws[7];
    int m = cursor[b * CSTRIDE];
    if (b == 0 && t == 0) row_ptr[N] = E;
    const int* bb = bkt + b * CAP;
    const int4* bb4 = (const int4*)bb;          // CAP%4==0 -> aligned
    int m4 = m >> 2;
    for (int j = t; j < m4; j += BT) {
        int4 v = bb4[j];
        atomicAdd(&cnt[v.x >> 17], 1); atomicAdd(&cnt[v.y >> 17], 1);
        atomicAdd(&cnt[v.z >> 17], 1); atomicAdd(&cnt[v.w >> 17], 1);
    }
    for (int j = (m4 << 2) + t; j < m; j += BT) atomicAdd(&cnt[bb[j] >> 17], 1);
    __syncthreads();
    int h = cnt[t];
    int v = h;
#pragma unroll
    for (int off = 1; off < 64; off <<= 1) {
        int u = __shfl_up(v, off);
        if (lane >= off) v += u;
    }
    if (lane == 63) ws[t >> 6] = v;
    __syncthreads();
    int add = 0;
    for (int i = 0; i < (t >> 6); ++i) add += ws[i];
    int ex = v + add - h;                       // exclusive prefix of bin t
    excl[t] = ex;
    int node = b * 512 + t;
    if (node < N) {
        row_ptr[node] = base + ex;
        dinv[node] = rsqrtf((float)(h + 1));
    }
    __syncthreads();
    for (int j = t; j < m4; j += BT) {
        int4 v4 = bb4[j];
        int p0 = atomicAdd(&excl[v4.x >> 17], 1); csr_src[base + p0] = v4.x & 0x1FFFF;
        int p1 = atomicAdd(&excl[v4.y >> 17], 1); csr_src[base + p1] = v4.y & 0x1FFFF;
        int p2 = atomicAdd(&excl[v4.z >> 17], 1); csr_src[base + p2] = v4.z & 0x1FFFF;
        int p3 = atomicAdd(&excl[v4.w >> 17], 1); csr_src[base + p3] = v4.w & 0x1FFFF;
    }
    for (int j = (m4 << 2) + t; j < m; j += BT) {
        int vv = bb[j];
        int p = atomicAdd(&excl[vv >> 17], 1);
        csr_src[base + p] = vv & 0x1FFFF;
    }
}

// h1s[row][c] = (X[row] . W1[:,c]) * dinv[row], stored bf16 (packed stores).
// Register double-buffer: next sweep's 4 X rows issued before the current
// tile's FMAs; lgkm-only wait keeps them in flight over compute.
__global__ void k_gemm1(const float* __restrict__ X, const float* __restrict__ W1,
                        const float* __restrict__ dinv, __hip_bfloat16* __restrict__ h1s,
                        __hip_bfloat16* __restrict__ h2s) {
    __shared__ float sX[4][4][64];              // [wave][row][feat]
    int t = threadIdx.x;
    int lane = t & 63;
    int w = t >> 6;
    int wid = (blockIdx.x * 256 + t) >> 6;      // 4096 waves
    if (blockIdx.x == 0) {
        if (t < 64) h1s[(size_t)N * 64 + t] = __float2bfloat16(0.f);
        if (t < 16) h2s[(size_t)N * 16 + t] = __float2bfloat16(0.f);
    }
    float w1[64];
#pragma unroll
    for (int k = 0; k < 64; ++k) w1[k] = W1[k * 64 + lane];
    constexpr int STRIDE = 4096 * 4;
    int r4 = wid * 4;
    float x0 = X[(size_t)r4 * 64 + lane];
    float x1 = X[(size_t)(r4 + 1) * 64 + lane];
    float x2 = X[(size_t)(r4 + 2) * 64 + lane];
    float x3 = X[(size_t)(r4 + 3) * 64 + lane];
    for (; r4 < N; r4 += STRIDE) {
        int rn = r4 + STRIDE;
        float y0 = 0.f, y1 = 0.f, y2 = 0.f, y3 = 0.f;
        if (rn < N) {                           // prefetch next sweep
            y0 = X[(size_t)rn * 64 + lane];
            y1 = X[(size_t)(rn + 1) * 64 + lane];
            y2 = X[(size_t)(rn + 2) * 64 + lane];
            y3 = X[(size_t)(rn + 3) * 64 + lane];
        }
        float dv0 = dinv[r4], dv1 = dinv[r4 + 1], dv2 = dinv[r4 + 2], dv3 = dinv[r4 + 3];
        sX[w][0][lane] = x0; sX[w][1][lane] = x1;
        sX[w][2][lane] = x2; sX[w][3][lane] = x3;
        wait_lgkm0();                           // y*/dv* stay in flight
        float acc0 = 0.f, acc1 = 0.f, acc2 = 0.f, acc3 = 0.f;
#pragma unroll
        for (int k = 0; k < 64; ++k) {          // 4 independent FMA chains
            float wk = w1[k];
            acc0 = fmaf(sX[w][0][k], wk, acc0);
            acc1 = fmaf(sX[w][1][k], wk, acc1);
            acc2 = fmaf(sX[w][2][k], wk, acc2);
            acc3 = fmaf(sX[w][3][k], wk, acc3);
        }
        acc0 *= dv0; acc1 *= dv1; acc2 *= dv2; acc3 *= dv3;
        float up0 = __shfl_xor(acc0, 1);
        float up1 = __shfl_xor(acc1, 1);
        float up2 = __shfl_xor(acc2, 1);
        float up3 = __shfl_xor(acc3, 1);
        if (!(lane & 1)) {
            __hip_bfloat162 p;
            p.x = __float2bfloat16(acc0); p.y = __float2bfloat16(up0);
            *(__hip_bfloat162*)(h1s + (size_t)r4 * 64 + lane) = p;
            p.x = __float2bfloat16(acc1); p.y = __float2bfloat16(up1);
            *(__hip_bfloat162*)(h1s + (size_t)(r4 + 1) * 64 + lane) = p;
            p.x = __float2bfloat16(acc2); p.y = __float2bfloat16(up2);
            *(__hip_bfloat162*)(h1s + (size_t)(r4 + 2) * 64 + lane) = p;
            p.x = __float2bfloat16(acc3); p.y = __float2bfloat16(up3);
            *(__hip_bfloat162*)(h1s + (size_t)(r4 + 3) * 64 + lane) = p;
        }
        x0 = y0; x1 = y1; x2 = y2; x3 = y3;
    }
}

// Fused: gather layer-1 (CSR), +b1, relu, y1@W2, scale -> h2s (bf16).
// Wave handles NPW contiguous nodes. 8 edges per uint4 load, 2-deep unroll;
// dummy zero row N pads — no predication, no divergence. (R11 structure.)
__global__ void k_layer12(const int* __restrict__ row_ptr, const int* __restrict__ csr_src,
                          const float* __restrict__ dinv, const __hip_bfloat16* __restrict__ h1s,
                          const float* __restrict__ b1, const float* __restrict__ W2,
                          __hip_bfloat16* __restrict__ h2s) {
    __shared__ float sy[4][8][72];
    int t = threadIdx.x;
    int lane = t & 63;
    int w = t >> 6;
    int g8 = lane >> 3;                         // edge sub-slot
    int qo = (lane & 7) << 4;                   // byte offset of 16B feat slice
    int g16 = lane >> 4, c16 = lane & 15;       // W2-stage layout
    int wid = blockIdx.x * 4 + w;
    int d0 = wid * NPW;
    if (d0 >= N) return;
    int dend = min(d0 + NPW, N);
    float w2[16];
#pragma unroll
    for (int j = 0; j < 16; ++j) w2[j] = W2[(g16 * 16 + j) * 16 + c16];
    float b1v = b1[lane];
    const char* Hb = (const char*)h1s;

    int rp0 = row_ptr[d0];
    for (int d = d0; d < dend; ++d) {
        int rp1 = row_ptr[d + 1];
        float dv = dinv[d];
        float a[8] = {0, 0, 0, 0, 0, 0, 0, 0};
        if (g8 == 0) {                          // self term (one 8-lane load)
            uint4 u = *(const uint4*)(Hb + (((unsigned)d << 7) | qo));
            a[0] = bflo(u.x); a[1] = bfhi(u.x); a[2] = bflo(u.y); a[3] = bfhi(u.y);
            a[4] = bflo(u.z); a[5] = bfhi(u.z); a[6] = bflo(u.w); a[7] = bfhi(u.w);
        }
        for (int base = rp0; base < rp1; base += 64) {   // wave-uniform bounds
            int nloc = min(64, rp1 - base);
            int sidx = (lane < nloc) ? csr_src[base + lane] : N;   // pad -> zero row
            int steps = (nloc + 15) >> 4;       // 16 edges / iter, 2 loads in flight
            for (int j = 0; j < steps; ++j) {
                int b0 = (j << 4) | g8;
                int s0 = __shfl(sidx, b0);
                int s1 = __shfl(sidx, b0 | 8);
                uint4 u0 = *(const uint4*)(Hb + (((unsigned)s0 << 7) | qo));
                uint4 u1 = *(const uint4*)(Hb + (((unsigned)s1 << 7) | qo));
                a[0] += bflo(u0.x); a[1] += bfhi(u0.x); a[2] += bflo(u0.y); a[3] += bfhi(u0.y);
                a[4] += bflo(u0.z); a[5] += bfhi(u0.z); a[6] += bflo(u0.w); a[7] += bfhi(u0.w);
                a[0] += bflo(u1.x); a[1] += bfhi(u1.x); a[2] += bflo(u1.y); a[3] += bfhi(u1.y);
                a[4] += bflo(u1.z); a[5] += bfhi(u1.z); a[6] += bflo(u1.w); a[7] += bfhi(u1.w);
            }
        }
        rp0 = rp1;
        // LDS transpose: partials (8 groups x 64 feats) -> y[feat=lane]
        float* row = &sy[w][g8][(lane & 7) << 3];
        *(float4*)row = make_float4(a[0], a[1], a[2], a[3]);
        *(float4*)(row + 4) = make_float4(a[4], a[5], a[6], a[7]);
        wait_lgkm0();                           // within-wave LDS order only
        float ysum = sy[w][0][lane] + sy[w][1][lane] + sy[w][2][lane] + sy[w][3][lane]
                   + sy[w][4][lane] + sy[w][5][lane] + sy[w][6][lane] + sy[w][7][lane];
        float y = fmaxf(fmaf(dv, ysum, b1v), 0.f);
        // h2[c] = sum_k y[k]*W2[k][c]; group g16 covers k = g16*16..+15
        float o = 0.f;
#pragma unroll
        for (int j = 0; j < 16; ++j) o = fmaf(__shfl(y, (lane & 48) | j), w2[j], o);
        o += __shfl_xor(o, 16);
        o += __shfl_xor(o, 32);
        o *= dv;
        float oup = __shfl_xor(o, 1);
        if (lane < 16 && !(lane & 1)) {
            __hip_bfloat162 p;
            p.x = __float2bfloat16(o);
            p.y = __float2bfloat16(oup);
            *(__hip_bfloat162*)(h2s + (size_t)d * 16 + lane) = p;
        }
    }
}

// out[d] = dinv[d]*(h2s[d] + sum_in h2s[s]) + b2.  16 edges per step (uint2,
// 4 lanes/edge), dummy-row padding, float4 stores. (R11 structure.)
__global__ void k_gather2(const int* __restrict__ row_ptr, const int* __restrict__ csr_src,
                          const float* __restrict__ dinv, const __hip_bfloat16* __restrict__ h2s,
                          const float* __restrict__ b2, float* __restrict__ out) {
    int t = threadIdx.x;
    int lane = t & 63;
    int g4 = lane >> 2;                         // edge slot within step
    int q2 = lane & 3;                          // 8B feat slice
    int qo = q2 << 3;
    int wid = blockIdx.x * 4 + (t >> 6);
    int d0 = wid * NPW;
    if (d0 >= N) return;
    int dend = min(d0 + NPW, N);
    float b2v[4];
#pragma unroll
    for (int k = 0; k < 4; ++k) b2v[k] = b2[q2 * 4 + k];
    const char* Hb = (const char*)h2s;

    int rp0 = row_ptr[d0];
    for (int d = d0; d < dend; ++d) {
        int rp1 = row_ptr[d + 1];
        float dv = dinv[d];
        float a[4] = {0, 0, 0, 0};
        if (g4 == 0) {                          // self term
            uint2 u = *(const uint2*)(Hb + (((unsigned)d << 5) | qo));
            a[0] = bflo(u.x); a[1] = bfhi(u.x); a[2] = bflo(u.y); a[3] = bfhi(u.y);
        }
        for (int base = rp0; base < rp1; base += 64) {
            int nloc = min(64, rp1 - base);
            int sidx = (lane < nloc) ? csr_src[base + lane] : N;
            int steps = (nloc + 15) >> 4;
            for (int j = 0; j < steps; ++j) {
                int s = __shfl(sidx, (j << 4) | g4);
                uint2 u = *(const uint2*)(Hb + (((unsigned)s << 5) | qo));
                a[0] += bflo(u.x); a[1] += bfhi(u.x);
                a[2] += bflo(u.y); a[3] += bfhi(u.y);
            }
        }
        rp0 = rp1;
#pragma unroll
        for (int k = 0; k < 4; ++k) {
            a[k] += __shfl_xor(a[k], 4);
            a[k] += __shfl_xor(a[k], 8);
            a[k] += __shfl_xor(a[k], 16);
            a[k] += __shfl_xor(a[k], 32);
        }
        if (lane < 4) {
            float4 r;
            r.x = fmaf(dv, a[0], b2v[0]);
            r.y = fmaf(dv, a[1], b2v[1]);
            r.z = fmaf(dv, a[2], b2v[2]);
            r.w = fmaf(dv, a[3], b2v[3]);
            *(float4*)(out + (size_t)d * 16 + q2 * 4) = r;
        }
    }
}

extern "C" void kernel_launch(void* const* d_in, const int* in_sizes, int n_in,
                              void* d_out, int out_size, void* d_ws, size_t ws_size,
                              hipStream_t stream) {
    const float* X  = (const float*)d_in[0];
    const int*   ei = (const int*)d_in[1];  // [2, E] int32: src then dst
    const float* W1 = (const float*)d_in[2];
    const float* b1 = (const float*)d_in[3];
    const float* W2 = (const float*)d_in[4];
    const float* b2 = (const float*)d_in[5];
    float* out = (float*)d_out;

    int* cursor  = (int*)d_ws;                     // NB*CSTRIDE = 6272
    int* row_ptr = cursor + NB * CSTRIDE;          // N+4 (pad keeps h1s 16B-aligned)
    int* bkt     = row_ptr + N + 4;                // NB*CAP
    int* csr_src = bkt + NB * CAP;                 // E
    float* dinv  = (float*)(csr_src + E);          // N
    __hip_bfloat16* h1s = (__hip_bfloat16*)(dinv + N);  // (N+1)*64, 16B-aligned
    __hip_bfloat16* h2s = h1s + (size_t)(N + 1) * 64;   // (N+1)*16, 16B-aligned

    const int* src = ei;
    const int* dst = ei + E;

    hipMemsetAsync(cursor, 0, NB * CSTRIDE * sizeof(int), stream);
    k_bfill<<<NBLK, BT, 0, stream>>>(src, dst, cursor, bkt);
    k_bfine<<<NB, BT, 0, stream>>>(cursor, bkt, row_ptr, dinv, csr_src);
    k_gemm1<<<1024, 256, 0, stream>>>(X, W1, dinv, h1s, h2s);
    k_layer12<<<NWBLK, 256, 0, stream>>>(row_ptr, csr_src, dinv, h1s, b1, W2, h2s);
    k_gather2<<<NWBLK, 256, 0, stream>>>(row_ptr, csr_src, dinv, h2s, b2, out);
}